// Round 12
// baseline (402.804 us; speedup 1.0000x reference)
//
#include <hip/hip_runtime.h>
#include <hip/hip_bf16.h>
#include <math.h>

#define NN 100000
#define NE 1600000

#define NBUCK 8
#define BSZ (NN / NBUCK)       // 12500
#define CHUNKS 64
#define CH_E (NE / CHUNKS)     // 25000
#define FILL_BLOCKS (NBUCK * CHUNKS)   // 512
#define GEMM_GRID ((NN / 16 + 3) / 4)  // 1563

#define SCAN_BLK 256
#define NB_SCAN ((NN + SCAN_BLK - 1) / SCAN_BLK)   // 391

#define R1_N (28 * 512)   // 14336
#define R2_N (56 * 512)   // 28672
#define R3_N (28 * 512)   // 14336
#define PREP_TOTAL (R1_N + R2_N + R3_N + 224)
#define PREP_BLOCKS ((PREP_TOTAL + 255) / 256)   // 225

typedef float f32x4 __attribute__((ext_vector_type(4)));
typedef short s16x8 __attribute__((ext_vector_type(8)));
typedef unsigned short u16x4 __attribute__((ext_vector_type(4)));
typedef unsigned short u16x8 __attribute__((ext_vector_type(8)));
typedef int i32x4 __attribute__((ext_vector_type(4)));

static inline int grid_for(long total, int block, long cap = 16384) {
    long b = (total + block - 1) / block;
    if (b > cap) b = cap;
    if (b < 1) b = 1;
    return (int)b;
}

__device__ __forceinline__ unsigned short f2b(float f) {
    __hip_bfloat16 h = __float2bfloat16(f);   // round-to-nearest
    return __builtin_bit_cast(unsigned short, h);
}
__device__ __forceinline__ float b2f(unsigned short u) {
    unsigned int x = ((unsigned int)u) << 16;
    return __builtin_bit_cast(float, x);
}

// ================= weight repack helper =================
// W [K_REAL][N_REAL] f32 -> fragment-packed bf16 (zero-padded).
template <int K_REAL, int N_REAL, int NTILES>
__device__ __forceinline__ void repack_one(const float* __restrict__ W,
                                           unsigned short* __restrict__ Wf, int t) {
    int j = t & 7, lane = (t >> 3) & 63, frag = t >> 9;
    int kt = frag / NTILES, nt = frag - kt * NTILES;
    int k = kt * 32 + (lane >> 4) * 8 + j;
    int n = nt * 16 + (lane & 15);
    float v = (k < K_REAL && n < N_REAL) ? W[(size_t)k * N_REAL + n] : 0.0f;
    Wf[t] = f2b(v);
}

// ================= hist + weight prep (one dispatch) =================
// Blocks [0, FILL_BLOCKS): packed LDS histogram (src lo16, dst hi16) per
// (bucket g, chunk c); plain partial counts to scratch — no global atomics.
// Blocks [FILL_BLOCKS, +PREP_BLOCKS): weight repacks + bias pad.
__global__ __launch_bounds__(256) void hist_prep_kernel(
    const int* __restrict__ src, const int* __restrict__ dst, int* __restrict__ scratch,
    const float* __restrict__ W1, unsigned short* __restrict__ W1f,
    const float* __restrict__ W2, unsigned short* __restrict__ W2f,
    const float* __restrict__ W3, unsigned short* __restrict__ W3f,
    const float* __restrict__ b2, float* __restrict__ b2p)
{
    __shared__ int h[BSZ];   // 50 KB
    if (blockIdx.x >= FILL_BLOCKS) {
        int t = (blockIdx.x - FILL_BLOCKS) * 256 + threadIdx.x;
        if (t < R1_N) repack_one<128, 100, 7>(W1, W1f, t);
        else if (t < R1_N + R2_N) repack_one<100, 200, 14>(W2, W2f, t - R1_N);
        else if (t < R1_N + R2_N + R3_N) repack_one<200, 64, 4>(W3, W3f, t - R1_N - R2_N);
        else if (t < PREP_TOTAL) {
            int i = t - R1_N - R2_N - R3_N;
            b2p[i] = (i < 200) ? b2[i] : 0.0f;
        }
        return;
    }
    int g = blockIdx.x & 7, c = blockIdx.x >> 3;
    int lo = g * BSZ;
    for (int i = threadIdx.x; i < BSZ; i += 256) h[i] = 0;
    __syncthreads();
    const i32x4* src4 = reinterpret_cast<const i32x4*>(src + c * CH_E);
    const i32x4* dst4 = reinterpret_cast<const i32x4*>(dst + c * CH_E);
    for (int i = threadIdx.x; i < CH_E / 4; i += 256) {
        i32x4 s4 = src4[i];
        i32x4 d4 = dst4[i];
#pragma unroll
        for (int j = 0; j < 4; ++j) {
            unsigned si = (unsigned)(s4[j] - lo);
            unsigned di = (unsigned)(d4[j] - lo);
            if (si < BSZ) atomicAdd(&h[si], 1);
            if (di < BSZ) atomicAdd(&h[di], 0x10000);
        }
    }
    __syncthreads();
    int* o = scratch + ((size_t)g * CHUNKS + c) * BSZ;
    for (int i = threadIdx.x; i < BSZ; i += 256) o[i] = h[i];
}

// Sum chunk-partials per node -> norms + cnt_dst + per-block sums (fused).
__global__ void reduce_hist_kernel(const int* __restrict__ scratch,
                                   float* __restrict__ ns, float* __restrict__ nd,
                                   int* __restrict__ cnt_dst, int* __restrict__ partials) {
    __shared__ int sm[SCAN_BLK];
    int n = blockIdx.x * blockDim.x + threadIdx.x;
    int cdv = 0;
    if (n < NN) {
        int g = n / BSZ, i = n - g * BSZ;
        const int* p = scratch + (size_t)g * CHUNKS * BSZ + i;
        unsigned cs = 0, cd = 0;
#pragma unroll 8
        for (int c = 0; c < CHUNKS; ++c) {
            unsigned v = (unsigned)p[(size_t)c * BSZ];
            cs += v & 0xffffu;
            cd += v >> 16;
        }
        ns[n] = rsqrtf(fmaxf((float)cs, 1.0f));
        nd[n] = rsqrtf(fmaxf((float)cd, 1.0f));
        cnt_dst[n] = (int)cd;
        cdv = (int)cd;
    }
    sm[threadIdx.x] = cdv;
    __syncthreads();
    for (int s = SCAN_BLK / 2; s > 0; s >>= 1) {
        if (threadIdx.x < s) sm[threadIdx.x] += sm[threadIdx.x + s];
        __syncthreads();
    }
    if (threadIdx.x == 0) partials[blockIdx.x] = sm[0];
}

__global__ void scan_partials_kernel(int* __restrict__ p) {
    __shared__ int sm[512];
    int tid = threadIdx.x;
    int v = (tid < NB_SCAN) ? p[tid] : 0;
    sm[tid] = v;
    __syncthreads();
    for (int off = 1; off < 512; off <<= 1) {
        int t = (tid >= off) ? sm[tid - off] : 0;
        __syncthreads();
        sm[tid] += t;
        __syncthreads();
    }
    if (tid < NB_SCAN) p[tid] = sm[tid] - v;   // exclusive
}

// block scan -> row_ptr, then directly rewrite chunk-partials into start offsets.
__global__ void scan_offs_kernel(const int* __restrict__ cnt, const int* __restrict__ partials,
                                 int* __restrict__ row_ptr, int* __restrict__ scratch) {
    __shared__ int sm[SCAN_BLK];
    int i = blockIdx.x * SCAN_BLK + threadIdx.x;
    int v = (i < NN) ? cnt[i] : 0;
    sm[threadIdx.x] = v;
    __syncthreads();
    for (int off = 1; off < SCAN_BLK; off <<= 1) {
        int t = (threadIdx.x >= off) ? sm[threadIdx.x - off] : 0;
        __syncthreads();
        sm[threadIdx.x] += t;
        __syncthreads();
    }
    if (i < NN) {
        int excl = partials[blockIdx.x] + sm[threadIdx.x] - v;
        row_ptr[i] = excl;
        if (i == NN - 1) row_ptr[NN] = excl + v;
        int g = i / BSZ, ii = i - g * BSZ;
        int* pd = scratch + (size_t)g * CHUNKS * BSZ + ii;
        int base = excl;
#pragma unroll 8
        for (int c = 0; c < CHUNKS; ++c) {
            unsigned cc = ((unsigned)pd[(size_t)c * BSZ]) >> 16;
            pd[(size_t)c * BSZ] = base;
            base += (int)cc;
        }
    }
}

// ================= MFMA GEMM body (dense-A path) =================
// AMODE 0: A bf16 [NN][K_PAD].  AMODE 1: A f32 [NN][K_PAD], converted in-register.
// EPI 2: bf16 out[row*N_REAL + col] = acc * rowscale[row]  (col < N_REAL only)
template <int K_STEPS, int NTILES, int N_REAL, int K_PAD, int AMODE>
__device__ __forceinline__ void gemm_body(
    int wave, int lane, const void* __restrict__ Aptr,
    const unsigned short* __restrict__ Wf, const float* __restrict__ rowscale,
    void* __restrict__ outv)
{
    int row0 = wave << 4;
    if (row0 >= NN) return;
    int r = lane & 15, half = lane >> 4;

    f32x4 acc[NTILES];
#pragma unroll
    for (int nt = 0; nt < NTILES; ++nt) acc[nt] = (f32x4)(0.0f);

#pragma unroll
    for (int kt = 0; kt < K_STEPS; ++kt) {
        s16x8 a;
        if (AMODE == 0) {
            const unsigned short* arow = (const unsigned short*)Aptr
                + (size_t)(row0 + r) * K_PAD + half * 8 + kt * 32;
            a = *reinterpret_cast<const s16x8*>(arow);
        } else {
            const float* arow = (const float*)Aptr
                + (size_t)(row0 + r) * K_PAD + half * 8 + kt * 32;
            f32x4 alo = *reinterpret_cast<const f32x4*>(arow);
            f32x4 ahi = *reinterpret_cast<const f32x4*>(arow + 4);
#pragma unroll
            for (int j = 0; j < 4; ++j) {
                a[j]     = (short)f2b(alo[j]);
                a[4 + j] = (short)f2b(ahi[j]);
            }
        }
#pragma unroll
        for (int nt = 0; nt < NTILES; ++nt) {
            s16x8 b = *reinterpret_cast<const s16x8*>(
                Wf + (((kt * NTILES + nt) << 9) | (lane << 3)));
            acc[nt] = __builtin_amdgcn_mfma_f32_16x16x32_bf16(a, b, acc[nt], 0, 0, 0);
        }
    }

    int colbase = lane & 15;
    float rs[4];
#pragma unroll
    for (int j = 0; j < 4; ++j) rs[j] = rowscale[row0 + half * 4 + j];

    unsigned short* out = (unsigned short*)outv;
#pragma unroll
    for (int nt = 0; nt < NTILES; ++nt) {
        int col = nt * 16 + colbase;
        if (col < N_REAL) {
#pragma unroll
            for (int j = 0; j < 4; ++j) {
                int row = row0 + half * 4 + j;
                out[(size_t)row * N_REAL + col] = f2b(acc[nt][j] * rs[j]);
            }
        }
    }
}

template <int K_STEPS, int NTILES, int N_REAL, int K_PAD, int AMODE>
__global__ __launch_bounds__(256) void gemm_kernel(
    const void* __restrict__ Aptr, const unsigned short* __restrict__ Wf,
    const float* __restrict__ rowscale, void* __restrict__ outv)
{
    int wave = blockIdx.x * (blockDim.x >> 6) + (threadIdx.x >> 6);
    gemm_body<K_STEPS, NTILES, N_REAL, K_PAD, AMODE>(
        wave, threadIdx.x & 63, Aptr, Wf, rowscale, outv);
}

// ================= packed fill + gemm1 =================
__global__ __launch_bounds__(256) void fill_gemm1_kernel(
    const int* __restrict__ src, const int* __restrict__ dst,
    const int* __restrict__ scratch, int* __restrict__ col_src,
    const float* __restrict__ x, const unsigned short* __restrict__ W1f,
    const float* __restrict__ ns, unsigned short* __restrict__ y1)
{
    __shared__ int off[BSZ];   // 50 KB (unused by gemm blocks)
    if (blockIdx.x < FILL_BLOCKS) {
        int g = blockIdx.x & 7, c = blockIdx.x >> 3;
        int lo = g * BSZ;
        const int* pd = scratch + ((size_t)g * CHUNKS + c) * BSZ;
        for (int i = threadIdx.x; i < BSZ; i += 256) off[i] = pd[i];
        __syncthreads();
        const i32x4* src4 = reinterpret_cast<const i32x4*>(src + c * CH_E);
        const i32x4* dst4 = reinterpret_cast<const i32x4*>(dst + c * CH_E);
        for (int i = threadIdx.x; i < CH_E / 4; i += 256) {
            i32x4 s4 = src4[i];
            i32x4 d4 = dst4[i];
#pragma unroll
            for (int j = 0; j < 4; ++j) {
                unsigned di = (unsigned)(d4[j] - lo);
                if (di < BSZ) {
                    int p = atomicAdd(&off[di], 1);
                    col_src[p] = s4[j];
                }
            }
        }
    } else {
        int bid = blockIdx.x - FILL_BLOCKS;
        int wave = bid * 4 + (threadIdx.x >> 6);
        gemm_body<4, 7, 100, 128, 1>(wave, threadIdx.x & 63, x, W1f, ns, y1);
    }
}

// ================= fused gather2 + GEMM2 =================
// A-row n of the GEMM is gathered on the fly: Σ_{s∈N(n)} h1s[s] (f32 accum,
// bf16-rounded — numerics identical to the old agg2b materialization).
// Lane (r=lane&15, half=lane>>4) owns k-segments half*8 + kt*32 of row row0+r.
// h1s rows are 100 elements: kt<3 segments full; kt=3 -> half==0 has 4 valid
// elements (96..99), half>=1 all pad (zero).
__global__ __launch_bounds__(256) void gemm2_fused_kernel(
    const unsigned short* __restrict__ h1s, const int* __restrict__ row_ptr,
    const int* __restrict__ col_src, const unsigned short* __restrict__ Wf,
    const float* __restrict__ nd, const float* __restrict__ b2p,
    unsigned short* __restrict__ h2b)
{
    int wave = blockIdx.x * (blockDim.x >> 6) + (threadIdx.x >> 6);
    int row0 = wave << 4;
    if (row0 >= NN) return;
    int lane = threadIdx.x & 63;
    int r = lane & 15, half = lane >> 4;
    int n = row0 + r;
    int start = row_ptr[n], end = row_ptr[n + 1];

    f32x4 g0a = (f32x4)(0.f), g0b = (f32x4)(0.f);
    f32x4 g1a = (f32x4)(0.f), g1b = (f32x4)(0.f);
    f32x4 g2a = (f32x4)(0.f), g2b = (f32x4)(0.f);
    f32x4 g3a = (f32x4)(0.f);

    int i = start;
    for (; i + 2 <= end; i += 2) {
        int s0 = col_src[i], s1 = col_src[i + 1];
        const unsigned short* p0 = h1s + (size_t)s0 * 100 + half * 8;
        const unsigned short* p1 = h1s + (size_t)s1 * 100 + half * 8;
        u16x8 v00 = *reinterpret_cast<const u16x8*>(p0);
        u16x8 v01 = *reinterpret_cast<const u16x8*>(p0 + 32);
        u16x8 v02 = *reinterpret_cast<const u16x8*>(p0 + 64);
        u16x8 v10 = *reinterpret_cast<const u16x8*>(p1);
        u16x8 v11 = *reinterpret_cast<const u16x8*>(p1 + 32);
        u16x8 v12 = *reinterpret_cast<const u16x8*>(p1 + 64);
#pragma unroll
        for (int j = 0; j < 4; ++j) {
            g0a[j] += b2f(v00[j]) + b2f(v10[j]);
            g0b[j] += b2f(v00[4 + j]) + b2f(v10[4 + j]);
            g1a[j] += b2f(v01[j]) + b2f(v11[j]);
            g1b[j] += b2f(v01[4 + j]) + b2f(v11[4 + j]);
            g2a[j] += b2f(v02[j]) + b2f(v12[j]);
            g2b[j] += b2f(v02[4 + j]) + b2f(v12[4 + j]);
        }
        if (half == 0) {
            u16x4 w0 = *reinterpret_cast<const u16x4*>(p0 + 96);
            u16x4 w1 = *reinterpret_cast<const u16x4*>(p1 + 96);
#pragma unroll
            for (int j = 0; j < 4; ++j) g3a[j] += b2f(w0[j]) + b2f(w1[j]);
        }
    }
    for (; i < end; ++i) {
        int s0 = col_src[i];
        const unsigned short* p0 = h1s + (size_t)s0 * 100 + half * 8;
        u16x8 v00 = *reinterpret_cast<const u16x8*>(p0);
        u16x8 v01 = *reinterpret_cast<const u16x8*>(p0 + 32);
        u16x8 v02 = *reinterpret_cast<const u16x8*>(p0 + 64);
#pragma unroll
        for (int j = 0; j < 4; ++j) {
            g0a[j] += b2f(v00[j]);  g0b[j] += b2f(v00[4 + j]);
            g1a[j] += b2f(v01[j]);  g1b[j] += b2f(v01[4 + j]);
            g2a[j] += b2f(v02[j]);  g2b[j] += b2f(v02[4 + j]);
        }
        if (half == 0) {
            u16x4 w0 = *reinterpret_cast<const u16x4*>(p0 + 96);
#pragma unroll
            for (int j = 0; j < 4; ++j) g3a[j] += b2f(w0[j]);
        }
    }

    // convert gathered segments to bf16 A-fragments (same rounding as agg2b path)
    s16x8 a0, a1, a2, a3;
#pragma unroll
    for (int j = 0; j < 4; ++j) {
        a0[j] = (short)f2b(g0a[j]);  a0[4 + j] = (short)f2b(g0b[j]);
        a1[j] = (short)f2b(g1a[j]);  a1[4 + j] = (short)f2b(g1b[j]);
        a2[j] = (short)f2b(g2a[j]);  a2[4 + j] = (short)f2b(g2b[j]);
        a3[j] = (short)f2b(g3a[j]);  a3[4 + j] = 0;
    }
    if (half != 0) {
#pragma unroll
        for (int j = 0; j < 4; ++j) a3[j] = 0;
    }

    const int NTILES = 14;
    f32x4 acc[NTILES];
#pragma unroll
    for (int nt = 0; nt < NTILES; ++nt) acc[nt] = (f32x4)(0.0f);
#pragma unroll
    for (int nt = 0; nt < NTILES; ++nt) {
        s16x8 b0 = *reinterpret_cast<const s16x8*>(Wf + (((0 * NTILES + nt) << 9) | (lane << 3)));
        s16x8 b1 = *reinterpret_cast<const s16x8*>(Wf + (((1 * NTILES + nt) << 9) | (lane << 3)));
        s16x8 b2 = *reinterpret_cast<const s16x8*>(Wf + (((2 * NTILES + nt) << 9) | (lane << 3)));
        s16x8 b3 = *reinterpret_cast<const s16x8*>(Wf + (((3 * NTILES + nt) << 9) | (lane << 3)));
        acc[nt] = __builtin_amdgcn_mfma_f32_16x16x32_bf16(a0, b0, acc[nt], 0, 0, 0);
        acc[nt] = __builtin_amdgcn_mfma_f32_16x16x32_bf16(a1, b1, acc[nt], 0, 0, 0);
        acc[nt] = __builtin_amdgcn_mfma_f32_16x16x32_bf16(a2, b2, acc[nt], 0, 0, 0);
        acc[nt] = __builtin_amdgcn_mfma_f32_16x16x32_bf16(a3, b3, acc[nt], 0, 0, 0);
    }

    // epilogue: h2b[row][col] = elu(acc * nd[row] + b2p[col]), NOUT = 224
    int colbase = lane & 15;
    float rs[4];
#pragma unroll
    for (int j = 0; j < 4; ++j) rs[j] = nd[row0 + half * 4 + j];
#pragma unroll
    for (int nt = 0; nt < NTILES; ++nt) {
        int col = nt * 16 + colbase;
        float bv = b2p[col];
#pragma unroll
        for (int j = 0; j < 4; ++j) {
            int row = row0 + half * 4 + j;
            float v = acc[nt][j] * rs[j] + bv;
            v = (v > 0.0f) ? v : expm1f(v);
            h2b[(size_t)row * 224 + col] = f2b(v);
        }
    }
}

// ================= gathers (8 loads in flight, 4 accumulator chains) =================

#define GACC8(yb, stride)                                                        \
    int i = start;                                                               \
    f32x4 a0 = (f32x4)(0.0f), a1 = (f32x4)(0.0f), a2 = (f32x4)(0.0f),            \
          a3 = (f32x4)(0.0f);                                                    \
    for (; i + 8 <= end; i += 8) {                                               \
        int s0 = col_src[i],     s1 = col_src[i + 1];                            \
        int s2 = col_src[i + 2], s3 = col_src[i + 3];                            \
        int s4 = col_src[i + 4], s5 = col_src[i + 5];                            \
        int s6 = col_src[i + 6], s7 = col_src[i + 7];                            \
        u16x4 v0 = *reinterpret_cast<const u16x4*>(yb + (size_t)s0 * stride + g * 4); \
        u16x4 v1 = *reinterpret_cast<const u16x4*>(yb + (size_t)s1 * stride + g * 4); \
        u16x4 v2 = *reinterpret_cast<const u16x4*>(yb + (size_t)s2 * stride + g * 4); \
        u16x4 v3 = *reinterpret_cast<const u16x4*>(yb + (size_t)s3 * stride + g * 4); \
        u16x4 v4 = *reinterpret_cast<const u16x4*>(yb + (size_t)s4 * stride + g * 4); \
        u16x4 v5 = *reinterpret_cast<const u16x4*>(yb + (size_t)s5 * stride + g * 4); \
        u16x4 v6 = *reinterpret_cast<const u16x4*>(yb + (size_t)s6 * stride + g * 4); \
        u16x4 v7 = *reinterpret_cast<const u16x4*>(yb + (size_t)s7 * stride + g * 4); \
        _Pragma("unroll")                                                        \
        for (int j = 0; j < 4; ++j) {                                            \
            a0[j] += b2f(v0[j]) + b2f(v4[j]);                                    \
            a1[j] += b2f(v1[j]) + b2f(v5[j]);                                    \
            a2[j] += b2f(v2[j]) + b2f(v6[j]);                                    \
            a3[j] += b2f(v3[j]) + b2f(v7[j]);                                    \
        }                                                                        \
    }                                                                            \
    for (; i + 4 <= end; i += 4) {                                               \
        int s0 = col_src[i], s1 = col_src[i + 1];                                \
        int s2 = col_src[i + 2], s3 = col_src[i + 3];                            \
        u16x4 v0 = *reinterpret_cast<const u16x4*>(yb + (size_t)s0 * stride + g * 4); \
        u16x4 v1 = *reinterpret_cast<const u16x4*>(yb + (size_t)s1 * stride + g * 4); \
        u16x4 v2 = *reinterpret_cast<const u16x4*>(yb + (size_t)s2 * stride + g * 4); \
        u16x4 v3 = *reinterpret_cast<const u16x4*>(yb + (size_t)s3 * stride + g * 4); \
        _Pragma("unroll")                                                        \
        for (int j = 0; j < 4; ++j) {                                            \
            a0[j] += b2f(v0[j]); a1[j] += b2f(v1[j]);                            \
            a2[j] += b2f(v2[j]); a3[j] += b2f(v3[j]);                            \
        }                                                                        \
    }                                                                            \
    for (; i < end; ++i) {                                                       \
        int s0 = col_src[i];                                                     \
        u16x4 v0 = *reinterpret_cast<const u16x4*>(yb + (size_t)s0 * stride + g * 4); \
        _Pragma("unroll")                                                        \
        for (int j = 0; j < 4; ++j) a0[j] += b2f(v0[j]);                         \
    }                                                                            \
    f32x4 acc;                                                                   \
    _Pragma("unroll")                                                            \
    for (int j = 0; j < 4; ++j) acc[j] = (a0[j] + a1[j]) + (a2[j] + a3[j]);

// gather1: y1 bf16 [NN][100] -> h1s bf16 [NN][100];  h1s = elu(sum*nd + b1) * ns
__global__ void gather1_kernel(const unsigned short* __restrict__ y, const int* __restrict__ row_ptr,
                               const int* __restrict__ col_src, const float* __restrict__ ns,
                               const float* __restrict__ nd, const float* __restrict__ bias,
                               unsigned short* __restrict__ out) {
    unsigned t = blockIdx.x * blockDim.x + threadIdx.x;
    if (t >= NN * 25u) return;
    unsigned n = t / 25u, g = t - n * 25u;
    int start = row_ptr[n], end = row_ptr[n + 1];
    GACC8(y, 100)
    f32x4 b4 = *reinterpret_cast<const f32x4*>(bias + g * 4);
    float ndv = nd[n], nsv = ns[n];
    u16x4 o;
#pragma unroll
    for (int j = 0; j < 4; ++j) {
        float v = acc[j] * ndv + b4[j];
        v = (v > 0.0f) ? v : expm1f(v);
        o[j] = f2b(v * nsv);
    }
    *reinterpret_cast<u16x4*>(out + (size_t)n * 100 + g * 4) = o;
}

// gather3: y3 bf16 [NN][64] -> out f32 [NN][64];  out = sigmoid(sum*nd + b3)
__global__ void gather3_kernel(const unsigned short* __restrict__ y, const int* __restrict__ row_ptr,
                               const int* __restrict__ col_src, const float* __restrict__ nd,
                               const float* __restrict__ bias, float* __restrict__ out) {
    unsigned t = blockIdx.x * blockDim.x + threadIdx.x;
    if (t >= NN * 16u) return;
    unsigned n = t >> 4, g = t & 15u;
    int start = row_ptr[n], end = row_ptr[n + 1];
    GACC8(y, 64)
    f32x4 b4 = *reinterpret_cast<const f32x4*>(bias + g * 4);
    float ndv = nd[n];
    f32x4 o;
#pragma unroll
    for (int j = 0; j < 4; ++j) {
        float v = acc[j] * ndv + b4[j];
        o[j] = 1.0f / (1.0f + expf(-v));
    }
    *reinterpret_cast<f32x4*>(out + (size_t)n * 64 + g * 4) = o;
}

// ================= launch =================

extern "C" void kernel_launch(void* const* d_in, const int* in_sizes, int n_in,
                              void* d_out, int out_size, void* d_ws, size_t ws_size,
                              hipStream_t stream) {
    const float* x    = (const float*)d_in[0];
    const int*   esrc = (const int*)d_in[1];
    const int*   edst = (const int*)d_in[2];
    const float* W1   = (const float*)d_in[3];
    const float* b1   = (const float*)d_in[4];
    const float* W2   = (const float*)d_in[5];
    const float* b2   = (const float*)d_in[6];
    const float* W3   = (const float*)d_in[7];
    const float* b3   = (const float*)d_in[8];
    float* out = (float*)d_out;

    // ---- workspace carving (256B-aligned regions) ----
    char* base = (char*)d_ws;
    size_t off = 0;
    auto alloc = [&](size_t bytes) -> void* {
        void* p = base + off;
        off += (bytes + 255) & ~(size_t)255;
        return p;
    };
    // region1 (25.6 MB): scratch (packed hist -> offsets, preproc) -> y3 (bf16 [NN][64])
    void* region1 = alloc((size_t)NN * 128 * 2);
    // region2 (44.8 MB): y1 (bf16 [NN][100]) -> h2b (bf16 [NN][224])
    void* region2 = alloc((size_t)NN * 224 * 2);
    // region3 (20 MB): h1s (bf16 [NN][100])
    void* region3 = alloc((size_t)NN * 100 * 2);
    float* ns       = (float*)alloc(NN * 4);
    float* nd       = (float*)alloc(NN * 4);
    int*   cnt_dst  = (int*)alloc(NN * 4);
    int*   row_ptr  = (int*)alloc((NN + 1) * 4);
    int*   col_src  = (int*)alloc((size_t)NE * 4);
    int*   partials = (int*)alloc(512 * 4);
    unsigned short* W1f = (unsigned short*)alloc(R1_N * 2);
    unsigned short* W2f = (unsigned short*)alloc(R2_N * 2);
    unsigned short* W3f = (unsigned short*)alloc(R3_N * 2);
    float* b2p = (float*)alloc(224 * 4);

    int* scratch          = (int*)region1;   // 8*64*12500*4 = 25.6 MB, exact fit
    unsigned short* y3    = (unsigned short*)region1;
    unsigned short* y1    = (unsigned short*)region2;
    unsigned short* h2b   = (unsigned short*)region2;
    unsigned short* h1s   = (unsigned short*)region3;

    const int BLK = 256;

    // ---- hist + weight prep (one dispatch) ----
    hist_prep_kernel<<<FILL_BLOCKS + PREP_BLOCKS, 256, 0, stream>>>(
        esrc, edst, scratch, W1, W1f, W2, W2f, W3, W3f, b2, b2p);
    // ---- norms + block sums (fused), scan, block-scan + chunk offsets (fused) ----
    reduce_hist_kernel<<<NB_SCAN, SCAN_BLK, 0, stream>>>(scratch, ns, nd, cnt_dst, partials);
    scan_partials_kernel<<<1, 512, 0, stream>>>(partials);
    scan_offs_kernel<<<NB_SCAN, SCAN_BLK, 0, stream>>>(cnt_dst, partials, row_ptr, scratch);

    // ---- CSR fill packed with L1 GEMM (independent; overlap in one dispatch) ----
    fill_gemm1_kernel<<<FILL_BLOCKS + GEMM_GRID, 256, 0, stream>>>(
        esrc, edst, scratch, col_src, x, W1f, ns, y1);

    // h1s = elu(gather(y1)*nd + b1) * ns  (bf16 [NN][100])
    gather1_kernel<<<grid_for((long)NN * 25, BLK, 1 << 30), BLK, 0, stream>>>(
        y1, row_ptr, col_src, ns, nd, b1, h1s);

    // ---- L2 fused: h2 = elu((gather(h1s) @ W2)*nd + b2)  (bf16 [NN][224]) ----
    gemm2_fused_kernel<<<GEMM_GRID, 256, 0, stream>>>(
        h1s, row_ptr, col_src, W2f, nd, b2p, h2b);

    // ---- L3: y3 = (h2 @ W3) * ns  (bf16 [NN][64]) ----
    gemm_kernel<7, 4, 64, 224, 0><<<GEMM_GRID, BLK, 0, stream>>>(h2b, W3f, ns, y3);
    // out = sigmoid(gather(y3)*nd + b3)
    gather3_kernel<<<grid_for((long)NN * 16, BLK, 1 << 30), BLK, 0, stream>>>(
        y3, row_ptr, col_src, nd, b3, out);
}